// Round 1
// 382.661 us; speedup vs baseline: 1.1496x; 1.1496x over previous
//
#include <hip/hip_runtime.h>
#include <cstddef>

#define THRESH_V 10.0f
#define RPB 4          // rows per block: one wave (64 lanes) per row
#define SLICE 1040     // floats per wave slice (overlaid buffers, peak use 1031)

// Waves are fully independent (one row each, private LDS slice), so no block
// barrier is needed. Same-wave DS ops complete in order; this stops the
// compiler from moving LDS traffic across stage boundaries and drains the
// LDS queue so cross-lane values are register-visible.
static __device__ __forceinline__ void wave_sync() {
  asm volatile("s_waitcnt lgkmcnt(0)" ::: "memory");
}

// ---- reversed decomposition filters: R*[t] = DEC_*[7-t] ----
#define RLO0 ( 0.0322231006040427f)
#define RLO1 (-0.012603967262037833f)
#define RLO2 (-0.09921954357684722f)
#define RLO3 ( 0.29785779560527736f)
#define RLO4 ( 0.8037387518059161f)
#define RLO5 ( 0.49761866763201545f)
#define RLO6 (-0.02963552764599851f)
#define RLO7 (-0.07576571478927333f)
#define RHI0 (-0.07576571478927333f)
#define RHI1 ( 0.02963552764599851f)
#define RHI2 ( 0.49761866763201545f)
#define RHI3 (-0.8037387518059161f)
#define RHI4 ( 0.29785779560527736f)
#define RHI5 ( 0.09921954357684722f)
#define RHI6 (-0.012603967262037833f)
#define RHI7 (-0.0322231006040427f)

// Exact accumulation model preserved from the verified kernel:
//   p_t = fl(v_t * w_t)  (rounded products, NO fma)
//   y   = ((p0+p1)+(p2+p3)) + ((p4+p5)+(p6+p7))   (fixed pairwise tree)
// fp contract must stay OFF here: cA feeds later levels' threshold decisions.
static __device__ __forceinline__ float2 fwd_core(float v0, float v1, float v2,
                                                  float v3, float v4, float v5,
                                                  float v6, float v7) {
#pragma clang fp contract(off)
  float pl0 = v0 * RLO0, pl1 = v1 * RLO1, pl2 = v2 * RLO2, pl3 = v3 * RLO3;
  float pl4 = v4 * RLO4, pl5 = v5 * RLO5, pl6 = v6 * RLO6, pl7 = v7 * RLO7;
  float ph0 = v0 * RHI0, ph1 = v1 * RHI1, ph2 = v2 * RHI2, ph3 = v3 * RHI3;
  float ph4 = v4 * RHI4, ph5 = v5 * RHI5, ph6 = v6 * RHI6, ph7 = v7 * RHI7;
  float sLo = ((pl0 + pl1) + (pl2 + pl3)) + ((pl4 + pl5) + (pl6 + pl7));
  float sHi = ((ph0 + ph1) + (ph2 + ph3)) + ((ph4 + ph5) + (ph6 + ph7));
  return make_float2(sLo, sHi);
}

// symmetric-extension element fetch from de-interleaved storage
// E[j] = x[2j], O[j] = x[2j+1]; k in [-6, n+6]
static __device__ __forceinline__ float symget(const float* E, const float* O,
                                               int k, int n) {
  int idx = (k < 0) ? (-1 - k) : ((k >= n) ? (2 * n - 1 - k) : k);
  return (idx & 1) ? O[idx >> 1] : E[idx >> 1];
}

// Forward DWT stage on de-interleaved input (E/O halves of length-n signal).
// Outputs m=(n+7)/2 coefficients. cA written split (E/O) when SPLIT_OUT (it
// feeds another fwd stage) or interleaved otherwise (feeds the inverse).
// cD always interleaved (feeds the inverse), hard-thresholded.
// Interior outputs i in [3, (n-2)/2] need no symmetric extension:
//   v[t] = (t even) ? E[i-3 + t/2] : O[i-3 + (t-1)/2]
// -> two stride-1 4-float windows, lane-stride-1 LDS reads (conflict-free).
template <bool SPLIT_OUT>
static __device__ __forceinline__ void fwd_stage(const float* __restrict__ E,
                                                 const float* __restrict__ O,
                                                 int n,
                                                 float* __restrict__ caE,
                                                 float* __restrict__ caO,
                                                 float* __restrict__ cd,
                                                 int lane) {
  const int m = (n + 7) >> 1;
  const int iMax = (n - 2) >> 1;  // last sym-free output

  for (int i = 3 + lane; i <= iMax; i += 64) {
    const float* e = E + (i - 3);
    const float* o = O + (i - 3);
    float2 s = fwd_core(e[0], o[0], e[1], o[1], e[2], o[2], e[3], o[3]);
    if constexpr (SPLIT_OUT) {
      float* dst = (i & 1) ? caO : caE;
      dst[i >> 1] = s.x;
    } else {
      caE[i] = s.x;
    }
    cd[i] = (fabsf(s.y) <= THRESH_V) ? s.y : 0.f;
  }

  // boundary outputs: low {0,1,2}, high [iMax+1, m-1] (3 or 4 of them)
  int bi = -1;
  if (lane < 3) bi = lane;
  else if (lane >= 4 && lane < 8) {
    const int t = lane - 4;
    if (t < m - 1 - iMax) bi = iMax + 1 + t;
  }
  if (bi >= 0) {
    float v[8];
#pragma unroll
    for (int t = 0; t < 8; ++t) v[t] = symget(E, O, 2 * bi - 6 + t, n);
    float2 s = fwd_core(v[0], v[1], v[2], v[3], v[4], v[5], v[6], v[7]);
    if constexpr (SPLIT_OUT) {
      float* dst = (bi & 1) ? caO : caE;
      dst[bi >> 1] = s.x;
    } else {
      caE[bi] = s.x;
    }
    cd[bi] = (fabsf(s.y) <= THRESH_V) ? s.y : 0.f;
  }
}

// Inverse DWT stage, one even/odd output PAIR per lane: q=2t and q=2t+1 share
// j0=t, so ca[t..t+3]/cd[t..t+3] are loaded once (lane-stride-1, conflict-free)
// and the store is one aligned float2. No threshold decisions downstream and
// 0.81 output tolerance -> fmaf chains are fine here.
//   even q: sA = sum_p ca[t+p]*LO[2p+1], sD = sum_p cd[t+p]*HI[2p+1]
//   odd  q: sA = sum_p ca[t+p]*LO[2p],   sD = sum_p cd[t+p]*HI[2p]
static __device__ __forceinline__ void inv_stage(const float* __restrict__ ca,
                                                 const float* __restrict__ cd,
                                                 float* __restrict__ dst,
                                                 int outLen, int lane) {
  const int pairs = (outLen + 1) >> 1;
  for (int t = lane; t < pairs; t += 64) {
    float a0 = ca[t], a1 = ca[t + 1], a2 = ca[t + 2], a3 = ca[t + 3];
    float e0 = cd[t], e1 = cd[t + 1], e2 = cd[t + 2], e3 = cd[t + 3];
    // LO = DEC_LO, HI = DEC_HI (reconstruction uses the same taps as the ref)
    float se = fmaf(a0, -0.02963552764599851f,
               fmaf(a1,  0.8037387518059161f,
               fmaf(a2, -0.09921954357684722f, a3 *  0.0322231006040427f)))
             + fmaf(e0, -0.012603967262037833f,
               fmaf(e1,  0.29785779560527736f,
               fmaf(e2,  0.49761866763201545f, e3 * -0.07576571478927333f)));
    float so = fmaf(a0, -0.07576571478927333f,
               fmaf(a1,  0.49761866763201545f,
               fmaf(a2,  0.29785779560527736f, a3 * -0.012603967262037833f)))
             + fmaf(e0, -0.0322231006040427f,
               fmaf(e1,  0.09921954357684722f,
               fmaf(e2, -0.8037387518059161f,  e3 *  0.02963552764599851f)));
    const int q = 2 * t;
    if (q + 1 < outLen) {
      *reinterpret_cast<float2*>(dst + q) = make_float2(se, so);
    } else {
      dst[q] = se;  // odd outLen tail
    }
  }
}

// One wave per row; whole pipeline in a private LDS slice with overlaid
// buffers (floats, peak live = 1031):
//   [0,512)   sx E/O        -> after fwd1: ca2 E/O [0,133) + d2 [133,266)
//                              + ca3 E/O [266,336) + d3 [336,406)
//                              + ca4 [406,444) + d4 [444,482)
//                              -> after fwd3: rec133 [0,133)
//   [512,772) ca1 E/O       -> after fwd2: rec70 [512,582) -> rec259 [512,771)
//   [772,1031) d1
__global__ __launch_bounds__(256, 8) void wavelet_denoise_kernel(
    const float* __restrict__ x, float* __restrict__ out, int nrows) {
  __shared__ float lds[RPB][SLICE];  // 16640 B/block -> occupancy capped by 32 waves/CU
  const int wave = threadIdx.x >> 6;
  const int lane = threadIdx.x & 63;
  const int row = blockIdx.x * RPB + wave;
  if (row >= nrows) return;  // no barriers anywhere -> early exit is safe

  float* S = lds[wave];
  float* sxE  = S;          // 256
  float* sxO  = S + 256;    // 256
  float* ca1E = S + 512;    // 130
  float* ca1O = S + 642;    // 130 (129 used)
  float* d1   = S + 772;    // 259 (ends 1031)
  float* ca2E = S + 0;      // 67  (sx dead)
  float* ca2O = S + 67;     // 66
  float* d2   = S + 133;    // 133 (ends 266)
  float* ca3E = S + 266;    // 35
  float* ca3O = S + 301;    // 35
  float* d3   = S + 336;    // 70  (ends 406)
  float* ca4  = S + 406;    // 38  (interleaved: feeds inverse)
  float* d4   = S + 444;    // 38  (ends 482)
  float* rec70  = S + 512;  // 70  (ca1 dead)
  float* rec133 = S + 0;    // 133 (ca2 dead; d2 at [133,266) still live)
  float* rec259 = S + 512;  // 259 (rec70 dead; d1 at [772,..) untouched)

  // load row: 512 floats via float4, scatter to even/odd halves as float2
  {
    const float4* src4 = reinterpret_cast<const float4*>(x + (size_t)row * 512);
    float2* dE = reinterpret_cast<float2*>(sxE);
    float2* dO = reinterpret_cast<float2*>(sxO);
    for (int c = lane; c < 128; c += 64) {
      float4 v = src4[c];
      dE[c] = make_float2(v.x, v.z);
      dO[c] = make_float2(v.y, v.w);
    }
  }
  wave_sync();

  // analysis: 512 -> 259 -> 133 -> 70 -> 38
  fwd_stage<true >(sxE,  sxO,  512, ca1E, ca1O,   d1, lane); wave_sync();
  fwd_stage<true >(ca1E, ca1O, 259, ca2E, ca2O,   d2, lane); wave_sync();
  fwd_stage<true >(ca2E, ca2O, 133, ca3E, ca3O,   d3, lane); wave_sync();
  fwd_stage<false>(ca3E, ca3O,  70, ca4,  nullptr, d4, lane); wave_sync();

  // synthesis: 38 -> 70 -> 133 -> 259 -> 512 (truncations folded into outLen)
  inv_stage(ca4,    d4, rec70,   70, lane); wave_sync();
  inv_stage(rec70,  d3, rec133, 133, lane); wave_sync();
  inv_stage(rec133, d2, rec259, 259, lane); wave_sync();
  inv_stage(rec259, d1, out + (size_t)row * 512, 512, lane);
}

extern "C" void kernel_launch(void* const* d_in, const int* in_sizes, int n_in,
                              void* d_out, int out_size, void* d_ws, size_t ws_size,
                              hipStream_t stream) {
  const float* x = (const float*)d_in[0];  // (nrows, 512) fp32
  float* out = (float*)d_out;              // (nrows, 512) fp32
  const int nrows = in_sizes[0] / 512;
  const int grid = (nrows + RPB - 1) / RPB;
  wavelet_denoise_kernel<<<dim3(grid), dim3(256), 0, stream>>>(x, out, nrows);
}

// Round 2
// 346.853 us; speedup vs baseline: 1.2683x; 1.1032x over previous
//
#include <hip/hip_runtime.h>
#include <cstddef>

typedef float f2 __attribute__((ext_vector_type(2)));

#define THRESH_V 10.0f
#define RPB 4          // rows per block: one wave (64 lanes) per row
#define SLICE 1064     // floats per wave slice (overlaid buffers with ext margins)

// Waves are fully independent (one row each, private LDS slice) -> no block
// barriers. lgkmcnt(0) drains this wave's DS queue so cross-lane LDS values
// are visible, and the "memory" clobber stops cross-stage motion.
static __device__ __forceinline__ void wave_sync() {
  asm volatile("s_waitcnt lgkmcnt(0)" ::: "memory");
}

// ---- decomposition filters ----
#define L0 (-0.07576571478927333f)
#define L1 (-0.02963552764599851f)
#define L2 ( 0.49761866763201545f)
#define L3 ( 0.8037387518059161f)
#define L4 ( 0.29785779560527736f)
#define L5 (-0.09921954357684722f)
#define L6 (-0.012603967262037833f)
#define L7 ( 0.0322231006040427f)
#define H0 (-0.0322231006040427f)
#define H1 (-0.012603967262037833f)
#define H2 ( 0.09921954357684722f)
#define H3 ( 0.29785779560527736f)
#define H4 (-0.8037387518059161f)
#define H5 ( 0.49761866763201545f)
#define H6 ( 0.02963552764599851f)
#define H7 (-0.07576571478927333f)
// reversed taps: RLO[t] = L(7-t), RHI[t] = H(7-t)

// Fill symmetric-extension margins of a de-interleaved array pair.
// E[j]=x[2j], O[j]=x[2j+1] for the length-n signal x; margins cover
// k in [-6,-1] (left) and [n, n+6] (right). Cross-mirror identities:
//   x[-1-j] = x[j], x[n+j] = x[n-1-j].
// Reads touch only base elements; writes touch only margins -> no intra-call
// hazard. 13 active lanes, one tiny masked block per stage.
static __device__ __forceinline__ void fill_ext(float* E, float* O, int n, int lane) {
  int k = 0;
  bool act = false;
  if (lane < 6)                      { k = -1 - lane;      act = true; }  // k=-1..-6
  else if (lane >= 8 && lane < 15)   { k = n + (lane - 8); act = true; }  // k=n..n+6
  if (act) {
    const int src = (k < 0) ? (-1 - k) : (2 * n - 1 - k);   // always a base index
    const float v = (src & 1) ? O[src >> 1] : E[src >> 1];
    if (k & 1) O[(k - 1) >> 1] = v;   // arithmetic shift handles negative k
    else       E[k >> 1] = v;
  }
}

// Forward DWT stage on de-interleaved ext input (valid j in [-3, ...]).
// ALL m=(n+7)/2 outputs are uniform interior now (margins pre-filled):
//   v[t] = ext[2i-6+t] -> E-window e[i-3..i], O-window o[i-3..i]
// Packed-f32 evaluation, bit-exact to the reference accumulation model:
//   p_t = fl(v_t * w_t)  (rounded products, NO fma)
//   y   = ((p0+p1)+(p2+p3)) + ((p4+p5)+(p6+p7))   (fixed pairwise tree)
// pk pairs: (p0,p2)=Ea*(RLO0,RLO2), (p1,p3)=Oa*(RLO1,RLO3);
//   t1 = pk_add -> (fl(p0+p1), fl(p2+p3))  — identical tree leaves.
// fp contract must stay OFF: cA feeds later levels' threshold decisions.
template <bool SPLIT_OUT>
static __device__ __forceinline__ void fwd_stage(const float* __restrict__ E,
                                                 const float* __restrict__ O,
                                                 int n,
                                                 float* __restrict__ caE,
                                                 float* __restrict__ caO,
                                                 float* __restrict__ cd,
                                                 int lane) {
#pragma clang fp contract(off)
  const f2 CLa = {L7, L5}, CLb = {L6, L4}, CLc = {L3, L1}, CLd = {L2, L0};
  const f2 CHa = {H7, H5}, CHb = {H6, H4}, CHc = {H3, H1}, CHd = {H2, H0};
  const int m = (n + 7) >> 1;
  // i == lane (mod 64) and 64 is even -> output parity is fixed per lane:
  float* const myCa = SPLIT_OUT ? ((lane & 1) ? caO : caE) : caE;
  for (int i = lane; i < m; i += 64) {
    const float* e = E + i - 3;
    const float* o = O + i - 3;
    f2 Ea; Ea.x = e[0]; Ea.y = e[1];   // ds_read2_b32 pairs
    f2 Eb; Eb.x = e[2]; Eb.y = e[3];
    f2 Oa; Oa.x = o[0]; Oa.y = o[1];
    f2 Ob; Ob.x = o[2]; Ob.y = o[3];
    f2 t1 = Ea * CLa + Oa * CLb;       // (p0+p1, p2+p3)
    f2 t2 = Eb * CLc + Ob * CLd;       // (p4+p5, p6+p7)
    const float sLo = (t1.x + t1.y) + (t2.x + t2.y);
    f2 s1 = Ea * CHa + Oa * CHb;
    f2 s2 = Eb * CHc + Ob * CHd;
    const float sHi = (s1.x + s1.y) + (s2.x + s2.y);
    if constexpr (SPLIT_OUT) myCa[i >> 1] = sLo;
    else                     caE[i] = sLo;
    cd[i] = (fabsf(sHi) <= THRESH_V) ? sHi : 0.f;   // hard threshold
  }
}

// Inverse DWT stage, one even/odd output PAIR per lane (q=2t, 2t+1 share the
// ca/cd[t..t+3] window). Packed-f32 with fma allowed (no threshold decisions
// downstream; 0.81 tolerance dwarfs ulp-level reassociation):
//   se = a.(L1,L3,L5,L7) + d.(H1,H3,H5,H7)
//   so = a.(L0,L2,L4,L6) + d.(H0,H2,H4,H6)
// Read windows fit the coefficient arrays exactly at every level (max index
// pairs+2 == m-1), so no margins are needed here.
static __device__ __forceinline__ void inv_stage(const float* __restrict__ ca,
                                                 const float* __restrict__ cd,
                                                 float* __restrict__ dst,
                                                 int outLen, int lane) {
#pragma clang fp contract(fast)
  const f2 SEa = {L1, L3}, SEb = {L5, L7}, SEc = {H1, H3}, SEd = {H5, H7};
  const f2 SOa = {L0, L2}, SOb = {L4, L6}, SOc = {H0, H2}, SOd = {H4, H6};
  const int pairs = (outLen + 1) >> 1;
  for (int t = lane; t < pairs; t += 64) {
    f2 a01; a01.x = ca[t];     a01.y = ca[t + 1];
    f2 a23; a23.x = ca[t + 2]; a23.y = ca[t + 3];
    f2 d01; d01.x = cd[t];     d01.y = cd[t + 1];
    f2 d23; d23.x = cd[t + 2]; d23.y = cd[t + 3];
    f2 mE = a01 * SEa + a23 * SEb + d01 * SEc + d23 * SEd;  // pk_mul + 3 pk_fma
    f2 mO = a01 * SOa + a23 * SOb + d01 * SOc + d23 * SOd;
    const float se = mE.x + mE.y;
    const float so = mO.x + mO.y;
    const int q = 2 * t;
    if (q + 1 < outLen) {
      f2 r; r.x = se; r.y = so;
      *reinterpret_cast<f2*>(dst + q) = r;   // 8B-aligned (q even, even bases)
    } else {
      dst[q] = se;  // odd outLen tail
    }
  }
}

// One wave per row. LDS slice (floats), ext arrays have 4-float front margin
// (base at +4; j=-3 -> buf+1) and the exact right margin; all float2 touch
// points sit at even float offsets (8B aligned):
//   sxE  buf [0,264)    base 4      sxO  buf [264,528)  base 268
//   ca1E buf [528,666)  base 532    ca1O buf [666,804)  base 670
//   d1       [804,1063)
// overlays in the dead sx region after fwd1:
//   ca2E buf [0,74)   base 4     ca2O buf [74,148)  base 78    d2 [148,281)
//   ca3E buf [282,326) base 286  ca3O buf [326,368) base 330   d3 [368,438)
//   ca4      [438,476)           d4       [476,514)
// synthesis overlays: rec70 [528,598), rec133 [0,134), rec259 [528,788)
__global__ __launch_bounds__(256, 8) void wavelet_denoise_kernel(
    const float* __restrict__ x, float* __restrict__ out, int nrows) {
  __shared__ float lds[RPB][SLICE];  // 17024 B/block
  const int wave = threadIdx.x >> 6;
  const int lane = threadIdx.x & 63;
  const int row = blockIdx.x * RPB + wave;
  if (row >= nrows) return;  // no block barriers -> early exit is safe

  float* S = lds[wave];
  float* sxE  = S + 4;    float* sxO  = S + 268;
  float* ca1E = S + 532;  float* ca1O = S + 670;
  float* d1   = S + 804;                      // 259
  float* ca2E = S + 4;    float* ca2O = S + 78;
  float* d2   = S + 148;                      // 133
  float* ca3E = S + 286;  float* ca3O = S + 330;
  float* d3   = S + 368;                      // 70
  float* ca4  = S + 438;  float* d4   = S + 476;  // 38 each (interleaved)
  float* rec70  = S + 528;   // 70   (ca1 dead)
  float* rec133 = S + 0;     // 133  (ca2/ca3 dead; d2 at [148,281) live)
  float* rec259 = S + 528;   // 259  (rec70 dead; d1 untouched)

  // load row: float4 global reads, scatter to even/odd halves as float2
  {
    const float4* src4 = reinterpret_cast<const float4*>(x + (size_t)row * 512);
    f2* dE = reinterpret_cast<f2*>(sxE);   // byte 16 + w*4256: 8B aligned
    f2* dO = reinterpret_cast<f2*>(sxO);
    for (int c = lane; c < 128; c += 64) {
      float4 v = src4[c];
      f2 a; a.x = v.x; a.y = v.z;
      f2 b; b.x = v.y; b.y = v.w;
      dE[c] = a;
      dO[c] = b;
    }
  }
  wave_sync();
  fill_ext(sxE, sxO, 512, lane);
  wave_sync();

  // analysis: 512 -> 259 -> 133 -> 70 -> 38 (ext refilled per level)
  fwd_stage<true >(sxE,  sxO,  512, ca1E, ca1O,   d1, lane); wave_sync();
  fill_ext(ca1E, ca1O, 259, lane);                           wave_sync();
  fwd_stage<true >(ca1E, ca1O, 259, ca2E, ca2O,   d2, lane); wave_sync();
  fill_ext(ca2E, ca2O, 133, lane);                           wave_sync();
  fwd_stage<true >(ca2E, ca2O, 133, ca3E, ca3O,   d3, lane); wave_sync();
  fill_ext(ca3E, ca3O, 70, lane);                            wave_sync();
  fwd_stage<false>(ca3E, ca3O,  70, ca4,  nullptr, d4, lane); wave_sync();

  // synthesis: 38 -> 70 -> 133 -> 259 -> 512 (truncations folded into outLen)
  inv_stage(ca4,    d4, rec70,   70, lane); wave_sync();
  inv_stage(rec70,  d3, rec133, 133, lane); wave_sync();
  inv_stage(rec133, d2, rec259, 259, lane); wave_sync();
  inv_stage(rec259, d1, out + (size_t)row * 512, 512, lane);
}

extern "C" void kernel_launch(void* const* d_in, const int* in_sizes, int n_in,
                              void* d_out, int out_size, void* d_ws, size_t ws_size,
                              hipStream_t stream) {
  const float* x = (const float*)d_in[0];  // (nrows, 512) fp32
  float* out = (float*)d_out;              // (nrows, 512) fp32
  const int nrows = in_sizes[0] / 512;
  const int grid = (nrows + RPB - 1) / RPB;
  wavelet_denoise_kernel<<<dim3(grid), dim3(256), 0, stream>>>(x, out, nrows);
}

// Round 4
// 342.993 us; speedup vs baseline: 1.2826x; 1.0113x over previous
//
#include <hip/hip_runtime.h>
#include <cstddef>

typedef float f2 __attribute__((ext_vector_type(2)));
typedef float f4 __attribute__((ext_vector_type(4)));
typedef _Float16 h2 __attribute__((ext_vector_type(2)));

#define THRESH_V 10.0f
#define WPB 2            // waves per block (128 threads); each wave = 2 rows
#define SLICE_F2 930     // f2 units per wave slice (7440 B; 11 blocks/CU = 22 waves)

// Waves are fully independent (one row-pair each, private LDS slice) -> no
// block barriers. lgkmcnt(0) drains this wave's DS queue so cross-lane LDS
// values are visible; "memory" clobber stops cross-stage code motion.
static __device__ __forceinline__ void wave_sync() {
  asm volatile("s_waitcnt lgkmcnt(0)" ::: "memory");
}

// ---- decomposition filters ----
#define L0f (-0.07576571478927333f)
#define L1f (-0.02963552764599851f)
#define L2f ( 0.49761866763201545f)
#define L3f ( 0.8037387518059161f)
#define L4f ( 0.29785779560527736f)
#define L5f (-0.09921954357684722f)
#define L6f (-0.012603967262037833f)
#define L7f ( 0.0322231006040427f)
#define H0f (-0.0322231006040427f)
#define H1f (-0.012603967262037833f)
#define H2f ( 0.09921954357684722f)
#define H3f ( 0.29785779560527736f)
#define H4f (-0.8037387518059161f)
#define H5f ( 0.49761866763201545f)
#define H6f ( 0.02963552764599851f)
#define H7f (-0.07576571478927333f)

// Fill symmetric-extension margins of a de-interleaved (E/O) row-pair array.
// E[j]=x[2j], O[j]=x[2j+1] (each element an f2 = 2 rows); margins cover
// k in [-6,-1] and [n, n+6]. x[-1-k]=x[k], x[n+k]=x[n-1-k]. Reads touch only
// base elements, writes only margins. 13 active lanes, pure copies (exact).
static __device__ __forceinline__ void fill_ext(f2* E, f2* O, int n, int lane) {
  int k = 0; bool act = false;
  if (lane < 6)                    { k = -1 - lane;      act = true; }  // -1..-6
  else if (lane >= 8 && lane < 15) { k = n + (lane - 8); act = true; }  // n..n+6
  if (act) {
    const int src = (k < 0) ? (-1 - k) : (2 * n - 1 - k);   // base index
    const f2 v = (src & 1) ? O[src >> 1] : E[src >> 1];
    if (k & 1) O[(k - 1) >> 1] = v;   // arithmetic shift handles negative k
    else       E[k >> 1] = v;
  }
}

// Forward DWT stage, row-pair packed, margins pre-filled -> ALL m=(n+7)/2
// outputs are uniform interior:  v[t] = ext[2i-6+t], t even from E, odd from O.
// Exact accumulation model per row (element-wise across the f2 row pair):
//   p_t = fl(v_t * w_t)   (rounded products, NO fma)
//   y   = ((p0+p1)+(p2+p3)) + ((p4+p5)+(p6+p7))   (fixed pairwise tree)
// RLO[t] = L(7-t), RHI[t] = H(7-t). fp contract stays OFF: cA feeds later
// levels' threshold decisions (bit-exactness required).
template <bool SPLIT_OUT, bool D16>
static __device__ __forceinline__ void fwd_stage(const f2* __restrict__ E,
                                                 const f2* __restrict__ O, int n,
                                                 f2* __restrict__ caE,
                                                 f2* __restrict__ caO,
                                                 void* __restrict__ cdv, int lane) {
#pragma clang fp contract(off)
  const int m = (n + 7) >> 1;
  f2* const cdf = (f2*)cdv;
  h2* const cdh = (h2*)cdv;
  // i == lane (mod 64), 64 even -> output parity fixed per lane:
  f2* const myCa = SPLIT_OUT ? ((lane & 1) ? caO : caE) : caE;
  for (int i = lane; i < m; i += 64) {
    const f2* e = E + i - 3;
    const f2* o = O + i - 3;
    f2 v0 = e[0], v2 = e[1], v4 = e[2], v6 = e[3];
    f2 v1 = o[0], v3 = o[1], v5 = o[2], v7 = o[3];
    f2 sLo = ((v0 * L7f + v1 * L6f) + (v2 * L5f + v3 * L4f)) +
             ((v4 * L3f + v5 * L2f) + (v6 * L1f + v7 * L0f));
    f2 sHi = ((v0 * H7f + v1 * H6f) + (v2 * H5f + v3 * H4f)) +
             ((v4 * H3f + v5 * H2f) + (v6 * H1f + v7 * H0f));
    if constexpr (SPLIT_OUT) myCa[i >> 1] = sLo;
    else                     caE[i] = sLo;
    // hard threshold, per row (decisions on exact f32 values)
    const float dx = (fabsf(sHi.x) <= THRESH_V) ? sHi.x : 0.f;
    const float dy = (fabsf(sHi.y) <= THRESH_V) ? sHi.y : 0.f;
    if constexpr (D16) {
      // d1 storage only; |d| <= 10 so f16 (RNE casts) keeps abs error < 0.01,
      // far under tolerance; d1 never feeds a threshold decision.
      h2 r; r.x = (_Float16)dx; r.y = (_Float16)dy;
      cdh[i] = r;
    } else {
      f2 d; d.x = dx; d.y = dy;
      cdf[i] = d;
    }
  }
}

// Inverse DWT stage, row-pair packed, one even/odd output pair per lane
// (q=2t,2t+1 share the ca/cd[t..t+3] window). fma allowed (no threshold
// decisions downstream; 0.81 tolerance dwarfs rounding).
//   even q: taps L1,L3,L5,L7 / H1,H3,H5,H7;  odd q: L0,L2,L4,L6 / H0,H2,H4,H6
// Windows fit the coefficient arrays exactly at every level (max t+3 == m-1).
template <bool D16, bool GOUT>
static __device__ __forceinline__ void inv_stage(const f2* __restrict__ ca,
                                                 const void* __restrict__ cdv,
                                                 f2* __restrict__ dst,
                                                 float* __restrict__ gA,
                                                 float* __restrict__ gB, bool hasB,
                                                 int outLen, int lane) {
#pragma clang fp contract(fast)
  const f2* const cf = (const f2*)cdv;
  const h2* const ch = (const h2*)cdv;
  const int pairs = (outLen + 1) >> 1;
  for (int t = lane; t < pairs; t += 64) {
    f2 a0 = ca[t], a1 = ca[t + 1], a2 = ca[t + 2], a3 = ca[t + 3];
    f2 e0, e1, e2, e3;
    if constexpr (D16) {
      h2 x0 = ch[t], x1 = ch[t + 1], x2 = ch[t + 2], x3 = ch[t + 3];
      e0.x = (float)x0.x; e0.y = (float)x0.y;
      e1.x = (float)x1.x; e1.y = (float)x1.y;
      e2.x = (float)x2.x; e2.y = (float)x2.y;
      e3.x = (float)x3.x; e3.y = (float)x3.y;
    } else {
      e0 = cf[t]; e1 = cf[t + 1]; e2 = cf[t + 2]; e3 = cf[t + 3];
    }
    f2 se = a0 * L1f + a1 * L3f + a2 * L5f + a3 * L7f +
            e0 * H1f + e1 * H3f + e2 * H5f + e3 * H7f;
    f2 so = a0 * L0f + a1 * L2f + a2 * L4f + a3 * L6f +
            e0 * H0f + e1 * H2f + e2 * H4f + e3 * H6f;
    const int q = 2 * t;
    if constexpr (GOUT) {
      *reinterpret_cast<float2*>(gA + q) = make_float2(se.x, so.x);
      if (hasB) *reinterpret_cast<float2*>(gB + q) = make_float2(se.y, so.y);
    } else {
      if (q + 1 < outLen) {
        f4 r; r.x = se.x; r.y = se.y; r.z = so.x; r.w = so.y;
        *reinterpret_cast<f4*>(dst + q) = r;   // 16B aligned (even base + even q)
      } else {
        dst[q] = se;  // odd outLen tail
      }
    }
  }
}

// One wave per ROW PAIR. LDS slice layout in f2 units (f2 = {rowA,rowB}):
//   sxE  base +4   j in [-3,259]   units [1,263]
//   sxO  base +268 j in [-3,258]   units [265,526]
//   ca1E base +531 j in [-3,132]   units [528,663]
//   ca1O base +667 j in [-3,132]   units [664,799]
//   d1   h2[259] at +800           units [800,930)   (f16 storage; see note)
// overlays after fwd1 (sx dead): ca2E base+4 [1,73], ca2O base+78 [75,147],
//   d2 +148 f2[133] [148,280], ca3E base+286 [283,324], ca3O base+328 [325,365],
//   d3 +366 f2[70] [366,435], ca4 +436 f2[38], d4 +474 f2[38] (ends 511)
// synthesis: rec70 +528 [528,597] (ca1 dead), rec133 +0 [0,132] (ca2/ca3 dead,
//   d2 live at [148,280]), rec259 +528 [528,786] (rec70 dead, d1 untouched)
__global__ __launch_bounds__(128, 8) void wavelet_denoise_kernel(
    const float* __restrict__ x, float* __restrict__ out, int nrows) {
  __shared__ __align__(16) f2 lds[WPB][SLICE_F2];  // 14880 B/block
  const int wave = threadIdx.x >> 6;
  const int lane = threadIdx.x & 63;
  const int nPairs = (nrows + 1) >> 1;
  const int pairId = blockIdx.x * WPB + wave;
  if (pairId >= nPairs) return;  // no block barriers -> early exit safe

  const int rA = 2 * pairId;
  const bool hasB = (rA + 1) < nrows;
  const int rBc = hasB ? rA + 1 : rA;  // clamp: duplicate A into .y if no B

  f2* Sp   = lds[wave];
  f2* sxE  = Sp + 4;    f2* sxO  = Sp + 268;
  f2* ca1E = Sp + 531;  f2* ca1O = Sp + 667;
  h2* d1   = (h2*)(Sp + 800);
  f2* ca2E = Sp + 4;    f2* ca2O = Sp + 78;
  f2* d2   = Sp + 148;
  f2* ca3E = Sp + 286;  f2* ca3O = Sp + 328;
  f2* d3   = Sp + 366;
  f2* ca4  = Sp + 436;  f2* d4   = Sp + 474;
  f2* rec70  = Sp + 528;
  f2* rec133 = Sp + 0;
  f2* rec259 = Sp + 528;

  // load row pair: float4 global reads, interleave rows into packed E/O
  {
    const float4* sA4 = reinterpret_cast<const float4*>(x + (size_t)rA * 512);
    const float4* sB4 = reinterpret_cast<const float4*>(x + (size_t)rBc * 512);
    for (int c = lane; c < 128; c += 64) {
      float4 a = sA4[c];
      float4 b = sB4[c];
      f4 ev; ev.x = a.x; ev.y = b.x; ev.z = a.z; ev.w = b.z;  // E[2c],E[2c+1]
      f4 ov; ov.x = a.y; ov.y = b.y; ov.z = a.w; ov.w = b.w;  // O[2c],O[2c+1]
      *reinterpret_cast<f4*>(sxE + 2 * c) = ev;   // 16B aligned
      *reinterpret_cast<f4*>(sxO + 2 * c) = ov;
    }
  }
  wave_sync();
  fill_ext(sxE, sxO, 512, lane); wave_sync();

  // analysis: 512 -> 259 -> 133 -> 70 -> 38 (margins refilled per level)
  fwd_stage<true,  true >(sxE,  sxO,  512, ca1E, ca1O, d1, lane); wave_sync();
  fill_ext(ca1E, ca1O, 259, lane);                                wave_sync();
  fwd_stage<true,  false>(ca1E, ca1O, 259, ca2E, ca2O, d2, lane); wave_sync();
  fill_ext(ca2E, ca2O, 133, lane);                                wave_sync();
  fwd_stage<true,  false>(ca2E, ca2O, 133, ca3E, ca3O, d3, lane); wave_sync();
  fill_ext(ca3E, ca3O, 70, lane);                                 wave_sync();
  fwd_stage<false, false>(ca3E, ca3O, 70, ca4, nullptr, d4, lane); wave_sync();

  // synthesis: 38 -> 70 -> 133 -> 259 -> 512 (truncations folded into outLen)
  float* gA = out + (size_t)rA * 512;
  float* gB = out + (size_t)rBc * 512;
  inv_stage<false, false>(ca4,    d4, rec70,  nullptr, nullptr, false,  70, lane);
  wave_sync();
  inv_stage<false, false>(rec70,  d3, rec133, nullptr, nullptr, false, 133, lane);
  wave_sync();
  inv_stage<false, false>(rec133, d2, rec259, nullptr, nullptr, false, 259, lane);
  wave_sync();
  inv_stage<true,  true >(rec259, d1, nullptr, gA, gB, hasB, 512, lane);
}

extern "C" void kernel_launch(void* const* d_in, const int* in_sizes, int n_in,
                              void* d_out, int out_size, void* d_ws, size_t ws_size,
                              hipStream_t stream) {
  const float* x = (const float*)d_in[0];  // (nrows, 512) fp32
  float* out = (float*)d_out;              // (nrows, 512) fp32
  const int nrows = in_sizes[0] / 512;
  const int nPairs = (nrows + 1) >> 1;
  const int grid = (nPairs + WPB - 1) / WPB;
  wavelet_denoise_kernel<<<dim3(grid), dim3(WPB * 64), 0, stream>>>(x, out, nrows);
}

// Round 5
// 341.360 us; speedup vs baseline: 1.2887x; 1.0048x over previous
//
#include <hip/hip_runtime.h>
#include <cstddef>

typedef float f2 __attribute__((ext_vector_type(2)));
typedef float f4 __attribute__((ext_vector_type(4)));
typedef _Float16 h2 __attribute__((ext_vector_type(2)));

#define THRESH_V 10.0f
#define WPB 2            // waves per block (128 threads); each wave = 2 rows
#define SLICE_F2 928     // f2 units per wave slice (7424 B; 11 blocks/CU = 22 waves)

// Waves are fully independent (one row-pair each, private LDS slice) -> no
// block barriers. lgkmcnt(0) drains this wave's DS queue so cross-lane LDS
// values are visible; "memory" clobber stops cross-stage code motion.
static __device__ __forceinline__ void wave_sync() {
  asm volatile("s_waitcnt lgkmcnt(0)" ::: "memory");
}

// ---- decomposition filters ----
#define L0f (-0.07576571478927333f)
#define L1f (-0.02963552764599851f)
#define L2f ( 0.49761866763201545f)
#define L3f ( 0.8037387518059161f)
#define L4f ( 0.29785779560527736f)
#define L5f (-0.09921954357684722f)
#define L6f (-0.012603967262037833f)
#define L7f ( 0.0322231006040427f)
#define H0f (-0.0322231006040427f)
#define H1f (-0.012603967262037833f)
#define H2f ( 0.09921954357684722f)
#define H3f ( 0.29785779560527736f)
#define H4f (-0.8037387518059161f)
#define H5f ( 0.49761866763201545f)
#define H6f ( 0.02963552764599851f)
#define H7f (-0.07576571478927333f)

static __device__ __forceinline__ f2 lo2(f4 w) { return __builtin_shufflevector(w, w, 0, 1); }
static __device__ __forceinline__ f2 hi2(f4 w) { return __builtin_shufflevector(w, w, 2, 3); }

// Forward DWT stage, INTERLEAVED row-pair layout: unit j = {rowA[j], rowB[j]}.
// Input ext array has symmetric margins pre-filled (units -6..N+6 as needed),
// so ALL M=(N+7)/2 outputs are uniform:  v[t] = ext[2i-6+t].
// Window = 8 consecutive f2 units at EVEN start -> 4x ds_read_b128.
// Exact accumulation model per row (element-wise across the f2 pair):
//   p_t = fl(v_t * w_t)   (rounded products, NO fma)
//   y   = ((p0+p1)+(p2+p3)) + ((p4+p5)+(p6+p7))   (fixed pairwise tree)
// RLO[t]=L(7-t), RHI[t]=H(7-t). fp contract OFF: cA feeds later thresholds.
// MARGINS: boundary lanes also write ca's mirror units (producer-side ext
// fill: ext[-1-j]=ca[j] j=0..5; ext[M+t]=ca[M-1-t] t=0..6 -> i>=M-7 writes
// ca[2M-1-i]) so no separate fill pass or extra sync is needed.
template <int N, bool MARGINS, bool D16>
static __device__ __forceinline__ void fwd_stage(const f2* __restrict__ in,
                                                 f2* __restrict__ ca,
                                                 void* __restrict__ cdv, int lane) {
#pragma clang fp contract(off)
  constexpr int M = (N + 7) >> 1;
  f2* const cdf = (f2*)cdv;
  h2* const cdh = (h2*)cdv;
#pragma unroll
  for (int k = 0; k * 64 < M; ++k) {
    const int i = lane + k * 64;
    if (i < M) {
      const f4* w = (const f4*)(in + 2 * i - 6);   // 16B aligned (even unit)
      const f4 w0 = w[0], w1 = w[1], w2 = w[2], w3 = w[3];
      const f2 v0 = lo2(w0), v1 = hi2(w0), v2 = lo2(w1), v3 = hi2(w1);
      const f2 v4 = lo2(w2), v5 = hi2(w2), v6 = lo2(w3), v7 = hi2(w3);
      f2 sLo = ((v0 * L7f + v1 * L6f) + (v2 * L5f + v3 * L4f)) +
               ((v4 * L3f + v5 * L2f) + (v6 * L1f + v7 * L0f));
      f2 sHi = ((v0 * H7f + v1 * H6f) + (v2 * H5f + v3 * H4f)) +
               ((v4 * H3f + v5 * H2f) + (v6 * H1f + v7 * H0f));
      ca[i] = sLo;
      if constexpr (MARGINS) {
        if (i < 6)      ca[-1 - i]        = sLo;   // left mirror
        if (i >= M - 7) ca[2 * M - 1 - i] = sLo;   // right mirror
      }
      // hard threshold per row (decisions on exact f32 values)
      const float dx = (fabsf(sHi.x) <= THRESH_V) ? sHi.x : 0.f;
      const float dy = (fabsf(sHi.y) <= THRESH_V) ? sHi.y : 0.f;
      if constexpr (D16) {
        // d1 storage only; |d|<=10 so f16 RNE keeps abs err <0.01, far under
        // tolerance; d1 never feeds a threshold decision.
        h2 r; r.x = (_Float16)dx; r.y = (_Float16)dy;
        cdh[i] = r;
      } else {
        f2 d; d.x = dx; d.y = dy;
        cdf[i] = d;
      }
    }
  }
}

// Inverse DWT stage, row-pair packed, one even/odd output pair per lane
// (q=2t,2t+1 share the ca/cd[t..t+3] window). fma allowed (no threshold
// decisions downstream; 0.81 tolerance dwarfs rounding).
//   even q: taps L1,L3,L5,L7 / H1,H3,H5,H7;  odd q: L0,L2,L4,L6 / H0,H2,H4,H6
// Windows fit the coefficient arrays exactly at every level (max t+3 == M-1).
template <int OUTLEN, bool D16, bool GOUT>
static __device__ __forceinline__ void inv_stage(const f2* __restrict__ ca,
                                                 const void* __restrict__ cdv,
                                                 f2* __restrict__ dst,
                                                 float* __restrict__ gA,
                                                 float* __restrict__ gB, bool hasB,
                                                 int lane) {
#pragma clang fp contract(fast)
  const f2* const cf = (const f2*)cdv;
  const h2* const ch = (const h2*)cdv;
  constexpr int PAIRS = (OUTLEN + 1) >> 1;
#pragma unroll
  for (int k = 0; k * 64 < PAIRS; ++k) {
    const int t = lane + k * 64;
    if (t < PAIRS) {
      f2 a0 = ca[t], a1 = ca[t + 1], a2 = ca[t + 2], a3 = ca[t + 3];
      f2 e0, e1, e2, e3;
      if constexpr (D16) {
        h2 x0 = ch[t], x1 = ch[t + 1], x2 = ch[t + 2], x3 = ch[t + 3];
        e0.x = (float)x0.x; e0.y = (float)x0.y;
        e1.x = (float)x1.x; e1.y = (float)x1.y;
        e2.x = (float)x2.x; e2.y = (float)x2.y;
        e3.x = (float)x3.x; e3.y = (float)x3.y;
      } else {
        e0 = cf[t]; e1 = cf[t + 1]; e2 = cf[t + 2]; e3 = cf[t + 3];
      }
      f2 se = a0 * L1f + a1 * L3f + a2 * L5f + a3 * L7f +
              e0 * H1f + e1 * H3f + e2 * H5f + e3 * H7f;
      f2 so = a0 * L0f + a1 * L2f + a2 * L4f + a3 * L6f +
              e0 * H0f + e1 * H2f + e2 * H4f + e3 * H6f;
      const int q = 2 * t;
      if constexpr (GOUT) {
        *reinterpret_cast<float2*>(gA + q) = make_float2(se.x, so.x);
        if (hasB) *reinterpret_cast<float2*>(gB + q) = make_float2(se.y, so.y);
      } else {
        if (q + 1 < OUTLEN) {
          f4 r; r.x = se.x; r.y = se.y; r.z = so.x; r.w = so.y;
          *reinterpret_cast<f4*>(dst + q) = r;   // 16B aligned (even base + even q)
        } else {
          dst[q] = se;  // odd OUTLEN tail
        }
      }
    }
  }
}

// One wave per ROW PAIR. LDS slice in f2 units (unit j = {A[j],B[j]}),
// interleaved natural order, ext arrays carry [-6..+7] margins:
//   Region X [0,526):  sx base 6 (spans 0..524)
//     overlays after fwd1: ca2 base 6 [0..145], d2 146 [146..279],
//       ca3 base 286 [280..362], d3 364 [364..433], ca4 434, d4 472 (..509)
//     rec133 overlays [0..132] (ca2 dead; d2 still live)
//   Region Y [526,798): ca1 base 532 (spans 526..797)
//     rec70 [526..595] (ca1 dead), then rec259 [526..784]
//   Region Z [798,928): d1 = 260 h2 (f16 storage)
__global__ __launch_bounds__(128, 4) void wavelet_denoise_kernel(
    const float* __restrict__ x, float* __restrict__ out, int nrows) {
  __shared__ __align__(16) f2 lds[WPB][SLICE_F2];  // 14848 B/block
  const int wave = threadIdx.x >> 6;
  const int lane = threadIdx.x & 63;
  const int nPairs = (nrows + 1) >> 1;
  const int pairId = blockIdx.x * WPB + wave;
  if (pairId >= nPairs) return;  // no block barriers -> early exit safe

  const int rA = 2 * pairId;
  const bool hasB = (rA + 1) < nrows;
  const int rBc = hasB ? rA + 1 : rA;  // duplicate A into .y if no row B

  f2* Sp  = lds[wave];
  f2* sx  = Sp + 6;
  f2* ca2 = Sp + 6;    f2* d2 = Sp + 146;
  f2* ca3 = Sp + 286;  f2* d3 = Sp + 364;
  f2* ca4 = Sp + 434;  f2* d4 = Sp + 472;
  f2* ca1 = Sp + 532;
  h2* d1  = (h2*)(Sp + 798);
  f2* rec70  = Sp + 526;
  f2* rec133 = Sp + 0;
  f2* rec259 = Sp + 526;

  // Load row pair (float4 global reads), interleave rows into f2 units, and
  // write sx's symmetric margins directly from registers (lanes holding the
  // boundary chunks): ext[-1-j]=x[j], ext[512+t]=x[511-t].
  {
    const float4* sA4 = reinterpret_cast<const float4*>(x + (size_t)rA * 512);
    const float4* sB4 = reinterpret_cast<const float4*>(x + (size_t)rBc * 512);
#pragma unroll
    for (int kk = 0; kk < 2; ++kk) {
      const int c = lane + kk * 64;      // covers x[4c..4c+3]
      const float4 a = sA4[c];
      const float4 b = sB4[c];
      f4 u0; u0.x = a.x; u0.y = b.x; u0.z = a.y; u0.w = b.y;  // units 4c,4c+1
      f4 u1; u1.x = a.z; u1.y = b.z; u1.z = a.w; u1.w = b.w;  // units 4c+2,4c+3
      *reinterpret_cast<f4*>(sx + 4 * c)     = u0;   // 16B aligned
      *reinterpret_cast<f4*>(sx + 4 * c + 2) = u1;
      if (c == 0) {        // x[0..3] -> units -1..-4
        f4 m0; m0.x = a.y; m0.y = b.y; m0.z = a.x; m0.w = b.x;  // (-2:x[1], -1:x[0])
        *reinterpret_cast<f4*>(sx - 2) = m0;
        f4 m1; m1.x = a.w; m1.y = b.w; m1.z = a.z; m1.w = b.z;  // (-4:x[3], -3:x[2])
        *reinterpret_cast<f4*>(sx - 4) = m1;
      }
      if (c == 1) {        // x[4..5] -> units -5,-6
        f4 m; m.x = a.y; m.y = b.y; m.z = a.x; m.w = b.x;       // (-6:x[5], -5:x[4])
        *reinterpret_cast<f4*>(sx - 6) = m;
      }
      if (c == 127) {      // x[508..511] -> units 512..515
        f4 m0; m0.x = a.w; m0.y = b.w; m0.z = a.z; m0.w = b.z;  // (512:x[511],513:x[510])
        *reinterpret_cast<f4*>(sx + 512) = m0;
        f4 m1; m1.x = a.y; m1.y = b.y; m1.z = a.x; m1.w = b.x;  // (514:x[509],515:x[508])
        *reinterpret_cast<f4*>(sx + 514) = m1;
      }
      if (c == 126) {      // x[505..507] -> units 516..518
        f4 m0; m0.x = a.w; m0.y = b.w; m0.z = a.z; m0.w = b.z;  // (516:x[507],517:x[506])
        *reinterpret_cast<f4*>(sx + 516) = m0;
        f2 m1; m1.x = a.y; m1.y = b.y;                          // (518:x[505])
        sx[518] = m1;
      }
    }
  }
  wave_sync();

  // analysis: 512 -> 259 -> 133 -> 70 -> 38 (producers fill their own margins)
  fwd_stage<512, true,  true >(sx,  ca1, d1, lane); wave_sync();
  fwd_stage<259, true,  false>(ca1, ca2, d2, lane); wave_sync();
  fwd_stage<133, true,  false>(ca2, ca3, d3, lane); wave_sync();
  fwd_stage< 70, false, false>(ca3, ca4, d4, lane); wave_sync();

  // synthesis: 38 -> 70 -> 133 -> 259 -> 512 (truncations folded into OUTLEN)
  float* gA = out + (size_t)rA * 512;
  float* gB = out + (size_t)rBc * 512;
  inv_stage< 70, false, false>(ca4,    d4, rec70,  nullptr, nullptr, false, lane);
  wave_sync();
  inv_stage<133, false, false>(rec70,  d3, rec133, nullptr, nullptr, false, lane);
  wave_sync();
  inv_stage<259, false, false>(rec133, d2, rec259, nullptr, nullptr, false, lane);
  wave_sync();
  inv_stage<512, true,  true >(rec259, d1, nullptr, gA, gB, hasB, lane);
}

extern "C" void kernel_launch(void* const* d_in, const int* in_sizes, int n_in,
                              void* d_out, int out_size, void* d_ws, size_t ws_size,
                              hipStream_t stream) {
  const float* x = (const float*)d_in[0];  // (nrows, 512) fp32
  float* out = (float*)d_out;              // (nrows, 512) fp32
  const int nrows = in_sizes[0] / 512;
  const int nPairs = (nrows + 1) >> 1;
  const int grid = (nPairs + WPB - 1) / WPB;
  wavelet_denoise_kernel<<<dim3(grid), dim3(WPB * 64), 0, stream>>>(x, out, nrows);
}

// Round 6
// 339.109 us; speedup vs baseline: 1.2973x; 1.0066x over previous
//
#include <hip/hip_runtime.h>
#include <cstddef>

typedef float f2 __attribute__((ext_vector_type(2)));
typedef float f4 __attribute__((ext_vector_type(4)));
typedef _Float16 h2 __attribute__((ext_vector_type(2)));
typedef _Float16 h8 __attribute__((ext_vector_type(8)));

#define THRESH_V 10.0f
#define WPB 2            // waves per block (128 threads); each wave = 2 rows
#define SLICE_F2 930     // f2 units per wave slice (7440 B; 11 blocks/CU = 22 waves)

// Waves are fully independent (one row-pair each, private LDS slice) -> no
// block barriers. lgkmcnt(0) drains this wave's DS queue so cross-lane LDS
// values are visible; "memory" clobber stops cross-stage code motion.
static __device__ __forceinline__ void wave_sync() {
  asm volatile("s_waitcnt lgkmcnt(0)" ::: "memory");
}

// ---- decomposition filters ----
#define L0f (-0.07576571478927333f)
#define L1f (-0.02963552764599851f)
#define L2f ( 0.49761866763201545f)
#define L3f ( 0.8037387518059161f)
#define L4f ( 0.29785779560527736f)
#define L5f (-0.09921954357684722f)
#define L6f (-0.012603967262037833f)
#define L7f ( 0.0322231006040427f)
#define H0f (-0.0322231006040427f)
#define H1f (-0.012603967262037833f)
#define H2f ( 0.09921954357684722f)
#define H3f ( 0.29785779560527736f)
#define H4f (-0.8037387518059161f)
#define H5f ( 0.49761866763201545f)
#define H6f ( 0.02963552764599851f)
#define H7f (-0.07576571478927333f)

static __device__ __forceinline__ f2 lo2(f4 w) { return __builtin_shufflevector(w, w, 0, 1); }
static __device__ __forceinline__ f2 hi2(f4 w) { return __builtin_shufflevector(w, w, 2, 3); }
static __device__ __forceinline__ float thr(float x) {
  return (fabsf(x) <= THRESH_V) ? x : 0.f;
}

// Forward DWT stage, interleaved row-pair layout (unit j = {rowA[j],rowB[j]}),
// BLOCKED lane assignment: lane l computes outputs i0=B*l .. i0+B-1, reading
// ONE shared window of 2B+6 units (B+3 ds_read_b128) instead of 4B b128.
// Margins [-6, N+6] are pre-filled by the producer, so all M=(N+7)/2 outputs
// are uniform: v[t] = ext[2i-6+t].
// Exact accumulation model per row (element-wise across the f2 pair):
//   p_t = fl(v_t * w_t)   (rounded products, NO fma)
//   y   = ((p0+p1)+(p2+p3)) + ((p4+p5)+(p6+p7))   (fixed pairwise tree)
// RLO[t]=L(7-t), RHI[t]=H(7-t). fp contract OFF: cA feeds later thresholds.
// MARGINS: producers write ca's own mirrors (ext[-1-i]=ca[i] i<6;
// ext[2M-1-i]=ca[i] i>=M-7) as predicated scalar stores -> no extra sync.
template <int N, int B, bool MARGINS, bool D16>
static __device__ __forceinline__ void fwd_stage(const f2* __restrict__ in,
                                                 f2* __restrict__ ca,
                                                 void* __restrict__ cdv, int lane) {
#pragma clang fp contract(off)
  constexpr int M = (N + 7) >> 1;
  f2* const cdf = (f2*)cdv;
  h2* const cdh = (h2*)cdv;
  const int i0 = B * lane;
  if (i0 < M) {
    f2 w[2 * B + 6];
    const f4* p = (const f4*)(in + 2 * i0 - 6);   // even unit -> 16B aligned
#pragma unroll
    for (int k = 0; k < B + 3; ++k) {
      const f4 t = p[k];
      w[2 * k] = lo2(t);
      w[2 * k + 1] = hi2(t);
    }
    f2 sA[B], sD[B];
#pragma unroll
    for (int j = 0; j < B; ++j) {
      const f2 v0 = w[2*j+0], v1 = w[2*j+1], v2 = w[2*j+2], v3 = w[2*j+3];
      const f2 v4 = w[2*j+4], v5 = w[2*j+5], v6 = w[2*j+6], v7 = w[2*j+7];
      f2 sLo = ((v0 * L7f + v1 * L6f) + (v2 * L5f + v3 * L4f)) +
               ((v4 * L3f + v5 * L2f) + (v6 * L1f + v7 * L0f));
      f2 sHi = ((v0 * H7f + v1 * H6f) + (v2 * H5f + v3 * H4f)) +
               ((v4 * H3f + v5 * H2f) + (v6 * H1f + v7 * H0f));
      sA[j] = sLo;
      f2 d; d.x = thr(sHi.x); d.y = thr(sHi.y);
      sD[j] = d;
      if constexpr (MARGINS) {
        const int i = i0 + j;
        if (i < 6)                 ca[-1 - i]        = sLo;   // left mirror
        if (i >= M - 7 && i < M)   ca[2 * M - 1 - i] = sLo;   // right mirror
      }
    }
    if (i0 + B <= M) {   // full block: vectorized stores
      if constexpr (B == 4) {
        f4 c0; c0.x=sA[0].x; c0.y=sA[0].y; c0.z=sA[1].x; c0.w=sA[1].y;
        f4 c1; c1.x=sA[2].x; c1.y=sA[2].y; c1.z=sA[3].x; c1.w=sA[3].y;
        *(f4*)(ca + i0)     = c0;
        *(f4*)(ca + i0 + 2) = c1;
        if constexpr (D16) {
          h8 hv;
          hv[0]=(_Float16)sD[0].x; hv[1]=(_Float16)sD[0].y;
          hv[2]=(_Float16)sD[1].x; hv[3]=(_Float16)sD[1].y;
          hv[4]=(_Float16)sD[2].x; hv[5]=(_Float16)sD[2].y;
          hv[6]=(_Float16)sD[3].x; hv[7]=(_Float16)sD[3].y;
          *(h8*)(cdh + i0) = hv;        // byte 4*i0 = 16*lane, 16B aligned
        } else {
          f4 d0; d0.x=sD[0].x; d0.y=sD[0].y; d0.z=sD[1].x; d0.w=sD[1].y;
          f4 d1; d1.x=sD[2].x; d1.y=sD[2].y; d1.z=sD[3].x; d1.w=sD[3].y;
          *(f4*)(cdf + i0)     = d0;
          *(f4*)(cdf + i0 + 2) = d1;
        }
      } else if constexpr (B == 2) {
        f4 c0; c0.x=sA[0].x; c0.y=sA[0].y; c0.z=sA[1].x; c0.w=sA[1].y;
        *(f4*)(ca + i0) = c0;           // i0 = 2*lane even
        if constexpr (D16) {
          h2 r0; r0.x=(_Float16)sD[0].x; r0.y=(_Float16)sD[0].y;
          h2 r1; r1.x=(_Float16)sD[1].x; r1.y=(_Float16)sD[1].y;
          cdh[i0] = r0; cdh[i0 + 1] = r1;
        } else {
          f4 d0; d0.x=sD[0].x; d0.y=sD[0].y; d0.z=sD[1].x; d0.w=sD[1].y;
          *(f4*)(cdf + i0) = d0;
        }
      } else {   // B==1 or B==3: scalar stores
#pragma unroll
        for (int j = 0; j < B; ++j) {
          ca[i0 + j] = sA[j];
          if constexpr (D16) {
            h2 r; r.x=(_Float16)sD[j].x; r.y=(_Float16)sD[j].y;
            cdh[i0 + j] = r;
          } else cdf[i0 + j] = sD[j];
        }
      }
    } else {   // partial block (last active lane): scalar guarded stores
#pragma unroll
      for (int j = 0; j < B; ++j) {
        const int i = i0 + j;
        if (i < M) {
          ca[i] = sA[j];
          if constexpr (D16) {
            h2 r; r.x=(_Float16)sD[j].x; r.y=(_Float16)sD[j].y;
            cdh[i] = r;
          } else cdf[i] = sD[j];
        }
      }
    }
  }
  if constexpr (64 * B < M) {   // tail outputs (fwd1 only: 3), scattered
    const int it = 64 * B + lane;
    if (it < M) {
      f2 w2[8];
      const f4* p2 = (const f4*)(in + 2 * it - 6);
#pragma unroll
      for (int k = 0; k < 4; ++k) { const f4 t = p2[k]; w2[2*k]=lo2(t); w2[2*k+1]=hi2(t); }
      const f2 v0=w2[0],v1=w2[1],v2=w2[2],v3=w2[3],v4=w2[4],v5=w2[5],v6=w2[6],v7=w2[7];
      f2 sLo = ((v0 * L7f + v1 * L6f) + (v2 * L5f + v3 * L4f)) +
               ((v4 * L3f + v5 * L2f) + (v6 * L1f + v7 * L0f));
      f2 sHi = ((v0 * H7f + v1 * H6f) + (v2 * H5f + v3 * H4f)) +
               ((v4 * H3f + v5 * H2f) + (v6 * H1f + v7 * H0f));
      ca[it] = sLo;
      if constexpr (MARGINS) {
        if (it >= M - 7) ca[2 * M - 1 - it] = sLo;   // tail is in right-mirror zone
      }
      f2 d; d.x = thr(sHi.x); d.y = thr(sHi.y);
      if constexpr (D16) {
        h2 r; r.x=(_Float16)d.x; r.y=(_Float16)d.y;
        cdh[it] = r;
      } else cdf[it] = d;
    }
  }
}

// Inverse DWT stage, BLOCKED: lane l handles pairs t0=B*l .. t0+B-1 (outputs
// q=2t..2t+1), reading the shared window ca/cd[t0..t0+B+2] once.
// fma allowed (no threshold decisions downstream; 0.81 tolerance).
//   even q: taps L1,L3,L5,L7 / H1,H3,H5,H7;  odd q: L0,L2,L4,L6 / H0,H2,H4,H6
template <int OUT, int B, bool D16, bool GOUT>
static __device__ __forceinline__ void inv_stage(const f2* __restrict__ ca,
                                                 const void* __restrict__ cdv,
                                                 f2* __restrict__ dst,
                                                 float* __restrict__ gA,
                                                 float* __restrict__ gB,
                                                 bool hasB, int lane) {
#pragma clang fp contract(fast)
  constexpr int P = (OUT + 1) >> 1;
  const f2* const cf = (const f2*)cdv;
  const h2* const ch = (const h2*)cdv;
  const int t0 = B * lane;
  if (t0 < P) {
    f2 a[B + 3], e[B + 3];
    if constexpr (B == 1) {   // odd lane start -> b64 loads
#pragma unroll
      for (int k = 0; k < 4; ++k) {
        a[k] = ca[t0 + k];
        if constexpr (D16) { const h2 hx = ch[t0+k]; e[k].x=(float)hx.x; e[k].y=(float)hx.y; }
        else e[k] = cf[t0 + k];
      }
    } else {                  // t0 = B*l even -> b128 window loads
      constexpr int NR = (B + 4) / 2;
      const f4* pa = (const f4*)(ca + t0);
#pragma unroll
      for (int k = 0; k < NR; ++k) {
        const f4 t = pa[k];
        if (2 * k     < B + 3) a[2 * k]     = lo2(t);
        if (2 * k + 1 < B + 3) a[2 * k + 1] = hi2(t);
      }
      if constexpr (D16) {    // d1: h2 array, read 8 halves as 2x b128
        const f4* ph = (const f4*)(ch + t0);   // byte 4*t0 = 16*lane
        const f4 r0 = ph[0], r1 = ph[1];
        const float rr[8] = {r0.x, r0.y, r0.z, r0.w, r1.x, r1.y, r1.z, r1.w};
#pragma unroll
        for (int k = 0; k < B + 3; ++k) {
          const h2 hx = __builtin_bit_cast(h2, rr[k]);
          e[k].x = (float)hx.x; e[k].y = (float)hx.y;
        }
      } else {
        const f4* pe = (const f4*)(cf + t0);
#pragma unroll
        for (int k = 0; k < NR; ++k) {
          const f4 t = pe[k];
          if (2 * k     < B + 3) e[2 * k]     = lo2(t);
          if (2 * k + 1 < B + 3) e[2 * k + 1] = hi2(t);
        }
      }
    }
    f2 SE[B], SO[B];
#pragma unroll
    for (int j = 0; j < B; ++j) {
      const f2 a0=a[j], a1=a[j+1], a2=a[j+2], a3=a[j+3];
      const f2 e0=e[j], e1=e[j+1], e2=e[j+2], e3=e[j+3];
      SE[j] = a0*L1f + a1*L3f + a2*L5f + a3*L7f +
              e0*H1f + e1*H3f + e2*H5f + e3*H7f;
      SO[j] = a0*L0f + a1*L2f + a2*L4f + a3*L6f +
              e0*H0f + e1*H2f + e2*H4f + e3*H6f;
    }
    if constexpr (GOUT) {   // B==4, OUT=512: all blocks full; global f4 stores
      const int q0 = 2 * t0;   // = 8*lane
      *reinterpret_cast<float4*>(gA + q0)     = make_float4(SE[0].x, SO[0].x, SE[1].x, SO[1].x);
      *reinterpret_cast<float4*>(gA + q0 + 4) = make_float4(SE[2].x, SO[2].x, SE[3].x, SO[3].x);
      if (hasB) {
        *reinterpret_cast<float4*>(gB + q0)     = make_float4(SE[0].y, SO[0].y, SE[1].y, SO[1].y);
        *reinterpret_cast<float4*>(gB + q0 + 4) = make_float4(SE[2].y, SO[2].y, SE[3].y, SO[3].y);
      }
    } else {
      const bool full = (t0 + B <= P) && (2 * (t0 + B) <= OUT);
      if (full) {
#pragma unroll
        for (int j = 0; j < B; ++j) {
          f4 r; r.x=SE[j].x; r.y=SE[j].y; r.z=SO[j].x; r.w=SO[j].y;
          *(f4*)(dst + 2 * (t0 + j)) = r;   // even unit -> 16B aligned
        }
      } else {
#pragma unroll
        for (int j = 0; j < B; ++j) {
          const int t = t0 + j;
          if (t < P) {
            const int q = 2 * t;
            dst[q] = SE[j];
            if (q + 1 < OUT) dst[q + 1] = SO[j];
          }
        }
      }
    }
  }
  if constexpr (64 * B < P) {   // tail pairs (inv3 only: 2), legacy b64 path
    const int tt = 64 * B + lane;
    if (tt < P) {
      const f2 a0=ca[tt], a1=ca[tt+1], a2=ca[tt+2], a3=ca[tt+3];
      f2 e0, e1, e2, e3;
      if constexpr (D16) {
        const h2 x0=ch[tt], x1=ch[tt+1], x2=ch[tt+2], x3=ch[tt+3];
        e0.x=(float)x0.x; e0.y=(float)x0.y; e1.x=(float)x1.x; e1.y=(float)x1.y;
        e2.x=(float)x2.x; e2.y=(float)x2.y; e3.x=(float)x3.x; e3.y=(float)x3.y;
      } else { e0=cf[tt]; e1=cf[tt+1]; e2=cf[tt+2]; e3=cf[tt+3]; }
      const f2 se = a0*L1f + a1*L3f + a2*L5f + a3*L7f +
                    e0*H1f + e1*H3f + e2*H5f + e3*H7f;
      const f2 so = a0*L0f + a1*L2f + a2*L4f + a3*L6f +
                    e0*H0f + e1*H2f + e2*H4f + e3*H6f;
      const int q = 2 * tt;
      dst[q] = se;
      if (q + 1 < OUT) dst[q + 1] = so;
    }
  }
}

// One wave per ROW PAIR. LDS slice in f2 units (unit j = {A[j],B[j]}):
//  Region X [0,524): sx base 6, ext [-6,517]
//    after fwd1: ca2 base 6 (ext [-6,139]), d2 @146 [0..133],
//                ca3 base 286 (ext [-6,77]), d3 @364 [0..71],
//                ca4 @436 [0..37], d4 @474 [0..37]
//    rec133 overlays [0,134) (ca2 dead; d2 still live)
//  Region Y [524,800): ca1 base 530, ext [-6,269]
//    rec70 @524 [0..71] (ca1 dead), then rec259 @524 [0..259]
//  Region Z [800,930): d1 = h2[260] (f16 storage; |d1|<=10, never thresholded)
__global__ __launch_bounds__(128, 5) void wavelet_denoise_kernel(
    const float* __restrict__ x, float* __restrict__ out, int nrows) {
  __shared__ __align__(16) f2 lds[WPB][SLICE_F2];  // 14880 B/block
  const int wave = threadIdx.x >> 6;
  const int lane = threadIdx.x & 63;
  const int nPairs = (nrows + 1) >> 1;
  const int pairId = blockIdx.x * WPB + wave;
  if (pairId >= nPairs) return;  // no block barriers -> early exit safe

  const int rA = 2 * pairId;
  const bool hasB = (rA + 1) < nrows;
  const int rBc = hasB ? rA + 1 : rA;  // duplicate A into .y if no row B

  f2* Sp  = lds[wave];
  f2* sx  = Sp + 6;
  f2* ca2 = Sp + 6;    f2* d2 = Sp + 146;
  f2* ca3 = Sp + 286;  f2* d3 = Sp + 364;
  f2* ca4 = Sp + 436;  f2* d4 = Sp + 474;
  f2* rec133 = Sp + 0;
  f2* ca1 = Sp + 530;
  f2* rec70  = Sp + 524;
  f2* rec259 = Sp + 524;
  h2* d1  = (h2*)(Sp + 800);

  // Load row pair (float4 global reads), interleave rows into f2 units, and
  // write sx's symmetric margins from registers: ext[-1-j]=x[j], ext[512+t]=x[511-t].
  {
    const float4* sA4 = reinterpret_cast<const float4*>(x + (size_t)rA * 512);
    const float4* sB4 = reinterpret_cast<const float4*>(x + (size_t)rBc * 512);
#pragma unroll
    for (int kk = 0; kk < 2; ++kk) {
      const int c = lane + kk * 64;      // covers x[4c..4c+3]
      const float4 a = sA4[c];
      const float4 b = sB4[c];
      f4 u0; u0.x = a.x; u0.y = b.x; u0.z = a.y; u0.w = b.y;  // units 4c,4c+1
      f4 u1; u1.x = a.z; u1.y = b.z; u1.z = a.w; u1.w = b.w;  // units 4c+2,4c+3
      *reinterpret_cast<f4*>(sx + 4 * c)     = u0;
      *reinterpret_cast<f4*>(sx + 4 * c + 2) = u1;
      if (c == 0) {        // x[0..3] -> units -1..-4
        f4 m0; m0.x = a.y; m0.y = b.y; m0.z = a.x; m0.w = b.x;  // (-2:x[1], -1:x[0])
        *reinterpret_cast<f4*>(sx - 2) = m0;
        f4 m1; m1.x = a.w; m1.y = b.w; m1.z = a.z; m1.w = b.z;  // (-4:x[3], -3:x[2])
        *reinterpret_cast<f4*>(sx - 4) = m1;
      }
      if (c == 1) {        // x[4..5] -> units -5,-6
        f4 m; m.x = a.y; m.y = b.y; m.z = a.x; m.w = b.x;       // (-6:x[5], -5:x[4])
        *reinterpret_cast<f4*>(sx - 6) = m;
      }
      if (c == 127) {      // x[508..511] -> units 512..515
        f4 m0; m0.x = a.w; m0.y = b.w; m0.z = a.z; m0.w = b.z;  // (512:x[511],513:x[510])
        *reinterpret_cast<f4*>(sx + 512) = m0;
        f4 m1; m1.x = a.y; m1.y = b.y; m1.z = a.x; m1.w = b.x;  // (514:x[509],515:x[508])
        *reinterpret_cast<f4*>(sx + 514) = m1;
      }
      if (c == 126) {      // x[506..507] -> units 516..517
        f4 m0; m0.x = a.w; m0.y = b.w; m0.z = a.z; m0.w = b.z;  // (516:x[507],517:x[506])
        *reinterpret_cast<f4*>(sx + 516) = m0;
      }
    }
  }
  wave_sync();

  // analysis: 512 -> 259 -> 133 -> 70 -> 38 (producers fill their own margins)
  fwd_stage<512, 4, true,  true >(sx,  ca1, d1, lane); wave_sync();
  fwd_stage<259, 3, true,  false>(ca1, ca2, d2, lane); wave_sync();
  fwd_stage<133, 2, true,  false>(ca2, ca3, d3, lane); wave_sync();
  fwd_stage< 70, 1, false, false>(ca3, ca4, d4, lane); wave_sync();

  // synthesis: 38 -> 70 -> 133 -> 259 -> 512 (truncations folded into OUT)
  float* gA = out + (size_t)rA * 512;
  float* gB = out + (size_t)rBc * 512;
  inv_stage< 70, 1, false, false>(ca4,    d4, rec70,  nullptr, nullptr, false, lane);
  wave_sync();
  inv_stage<133, 2, false, false>(rec70,  d3, rec133, nullptr, nullptr, false, lane);
  wave_sync();
  inv_stage<259, 2, false, false>(rec133, d2, rec259, nullptr, nullptr, false, lane);
  wave_sync();
  inv_stage<512, 4, true,  true >(rec259, d1, nullptr, gA, gB, hasB, lane);
}

extern "C" void kernel_launch(void* const* d_in, const int* in_sizes, int n_in,
                              void* d_out, int out_size, void* d_ws, size_t ws_size,
                              hipStream_t stream) {
  const float* x = (const float*)d_in[0];  // (nrows, 512) fp32
  float* out = (float*)d_out;              // (nrows, 512) fp32
  const int nrows = in_sizes[0] / 512;
  const int nPairs = (nrows + 1) >> 1;
  const int grid = (nPairs + WPB - 1) / WPB;
  wavelet_denoise_kernel<<<dim3(grid), dim3(WPB * 64), 0, stream>>>(x, out, nrows);
}